// Round 1
// baseline (156.183 us; speedup 1.0000x reference)
//
#include <hip/hip_runtime.h>

// TriangleAttentionStartingNode — MI355X gfx950. f32 global I/O, bf16 MFMA compute.
//
// R5: latency/occupancy round. R4 counters: MfmaUtil 8.8, VALUBusy 53,
// Occupancy 18 (2 waves/SIMD, LDS-capped), 9 barriers — latency-bound.
// Restructure: wave == head; K/V projection fused into the attention k-loop
// so K/V fragments stay in registers (the R4 sK/sVt load pattern was
// lane-identical to what the producing lane computed, so register-direct
// packing is bit-identical math). Removes sK/sVt (−35 KB LDS), all K/V
// LDS round-trips, and per-head barriers (9 -> 2). Cross-head out
// reduction via f32 ds_add into sO (bo folded into init). Grid 4x256
// (64 q/block), launch_bounds(256,3) -> target 3 waves/SIMD.
//
// Kept from R4: v_perm round-half-up bf16 packing; softmax scale*log2e
// folded into Q; no exp clamp (post-LN scores O(1)); Wb unused (softmax
// shift invariance); tree-reduced l with 2 shfl_xor.

typedef unsigned short u16;
typedef unsigned int   u32;
typedef __bf16 bf16x8 __attribute__((ext_vector_type(8)));
typedef float  f32x4  __attribute__((ext_vector_type(4)));

union U8 { bf16x8 b; u32 u[4]; };

// round-half-up f32->bf16 pair pack: 2 adds + 1 v_perm
__device__ __forceinline__ u32 pk(float a, float b) {
  const u32 au = __float_as_uint(a) + 0x8000u;
  const u32 bu = __float_as_uint(b) + 0x8000u;
  return __builtin_amdgcn_perm(bu, au, 0x07060302u);  // {b.hi16, a.hi16}
}
__device__ __forceinline__ f32x4 mfma16(bf16x8 a, bf16x8 b, f32x4 c) {
  return __builtin_amdgcn_mfma_f32_16x16x32_bf16(a, b, c, 0, 0, 0);
}

#define LDZ 40    // 80 B rows (16B-aligned for uint4 reads)

__global__ __launch_bounds__(256, 3) void tri_attn_fused(
    const float* __restrict__ z,  const float* __restrict__ ln_g, const float* __restrict__ ln_b,
    const float* __restrict__ Wq, const float* __restrict__ Wk,   const float* __restrict__ Wv,
    const float* __restrict__ Wg, const float* __restrict__ bg,
    const float* __restrict__ Wo, const float* __restrict__ bo,   float* __restrict__ out)
{
  __shared__ u16   sZ[256][LDZ];   // zn[pos][ch] bf16, all 256 positions of row i (20480 B)
  __shared__ float sO[64][33];     // f32 cross-head out reduction, +1 pad (8448 B)

  const int qq   = blockIdx.x;     // q-quarter: queries qq*64 .. qq*64+63
  const int i    = blockIdx.y;
  const int tid  = threadIdx.x;
  const int h    = tid >> 6;       // wave == head
  const int lane = tid & 63, quad = lane >> 4, col = lane & 15;
  const f32x4 z4 = {0.f, 0.f, 0.f, 0.f};

  // ---------------- phase 0: LayerNorm -> sZ; init sO = bo ----------------
  {
    const float* zr = z + (((i << 8) + tid) << 5);
    float x[32];
#pragma unroll
    for (int e = 0; e < 8; e++) {
      const float4 v = *(const float4*)(zr + e*4);
      x[4*e] = v.x; x[4*e+1] = v.y; x[4*e+2] = v.z; x[4*e+3] = v.w;
    }
    float mu = 0.f;
#pragma unroll
    for (int c = 0; c < 32; c++) mu += x[c];
    mu *= (1.f / 32.f);
    float s2 = 0.f;
#pragma unroll
    for (int c = 0; c < 32; c++) { float d = x[c] - mu; s2 += d * d; }
    const float rstd = rsqrtf(s2 * (1.f / 32.f) + 1e-5f);
    u32* dst = (u32*)&sZ[tid][0];
#pragma unroll
    for (int e = 0; e < 16; e++) {
      const float za = (x[2*e]   - mu) * rstd * ln_g[2*e]   + ln_b[2*e];
      const float zb = (x[2*e+1] - mu) * rstd * ln_g[2*e+1] + ln_b[2*e+1];
      dst[e] = pk(za, zb);
    }
    // sO init: bo broadcast into every q-row (pad col -> 0)
    float* p = &sO[0][0];
    for (int idx = tid; idx < 64*33; idx += 256) {
      const int c = idx % 33;
      p[idx] = (c < 32) ? bo[c] : 0.f;
    }
  }
  __syncthreads();   // barrier 1 of 2

  // per-head weight fragment loader (f32 -> bf16 pack), L1/L2-hot
  auto ldw = [&](const float* W, int cb) -> U8 {
    const float* p = W + h*1024 + (cb*16 + col)*32 + quad*8;
    const float4 a = *(const float4*)(p);
    const float4 b = *(const float4*)(p + 4);
    U8 t;
    t.u[0] = pk(a.x, a.y); t.u[1] = pk(a.z, a.w);
    t.u[2] = pk(b.x, b.y); t.u[3] = pk(b.z, b.w);
    return t;
  };

  // ---------------- Q, G for this wave's 4 q-tiles ----------------
  U8 QB[4];          // Q (pre-scaled by (1/sqrt32)*log2e) permuted-k B-frags
  float G[4][8];     // gates, O^T C-layout, kept f32 for precision
  {
    const U8 WqF0 = ldw(Wq,0), WqF1 = ldw(Wq,1);
    const U8 WgF0 = ldw(Wg,0), WgF1 = ldw(Wg,1);
    const float k2e = 0.17677669529663687f * 1.44269504089f;
    float bgl[8];
#pragma unroll
    for (int r = 0; r < 4; r++) {
      bgl[r]     = bg[h*32 + quad*4 + r];
      bgl[4 + r] = bg[h*32 + 16 + quad*4 + r];
    }
#pragma unroll
    for (int qt = 0; qt < 4; qt++) {
      const int row = (qq*4 + qt)*16 + col;
      U8 ZA;
      {
        const uint4 v = *(const uint4*)&sZ[row][quad*8];
        ZA.u[0] = v.x; ZA.u[1] = v.y; ZA.u[2] = v.z; ZA.u[3] = v.w;
      }
      const f32x4 q0 = mfma16(WqF0.b, ZA.b, z4);
      const f32x4 q1 = mfma16(WqF1.b, ZA.b, z4);
      const f32x4 g0 = mfma16(WgF0.b, ZA.b, z4);
      const f32x4 g1 = mfma16(WgF1.b, ZA.b, z4);
      QB[qt].u[0] = pk(q0[0]*k2e, q0[1]*k2e); QB[qt].u[1] = pk(q0[2]*k2e, q0[3]*k2e);
      QB[qt].u[2] = pk(q1[0]*k2e, q1[1]*k2e); QB[qt].u[3] = pk(q1[2]*k2e, q1[3]*k2e);
#pragma unroll
      for (int r = 0; r < 4; r++) {
        G[qt][r]     = 1.f / (1.f + __expf(-(g0[r] + bgl[r])));
        G[qt][4 + r] = 1.f / (1.f + __expf(-(g1[r] + bgl[4 + r])));
      }
    }
  }

  // -------- fused K/V projection + flash attention over all 256 keys --------
  const U8 WkF0 = ldw(Wk,0), WkF1 = ldw(Wk,1);
  const U8 WvF0 = ldw(Wv,0), WvF1 = ldw(Wv,1);
  f32x4 O0[4] = {z4, z4, z4, z4};   // O^T: ch=quad*4+r, q=col
  f32x4 O1[4] = {z4, z4, z4, z4};   // O^T: ch=16+quad*4+r
  float l[4]  = {0.f, 0.f, 0.f, 0.f};

#pragma unroll
  for (int kt = 0; kt < 256; kt += 32) {
    // project K,V for key-tiles kt and kt+16 (register-resident fragments;
    // packs are bit-identical to R4's sK/sVt store->load round trip)
    U8 ZAa, ZAb;
    {
      const uint4 va = *(const uint4*)&sZ[kt + col][quad*8];
      ZAa.u[0] = va.x; ZAa.u[1] = va.y; ZAa.u[2] = va.z; ZAa.u[3] = va.w;
      const uint4 vb = *(const uint4*)&sZ[kt + 16 + col][quad*8];
      ZAb.u[0] = vb.x; ZAb.u[1] = vb.y; ZAb.u[2] = vb.z; ZAb.u[3] = vb.w;
    }
    const f32x4 k0a = mfma16(WkF0.b, ZAa.b, z4);   // K^T: ch=quad*4+r, key=kt+col
    const f32x4 k1a = mfma16(WkF1.b, ZAa.b, z4);
    const f32x4 v0a = mfma16(ZAa.b, WvF0.b, z4);   // V: key=kt+quad*4+r, ch=col
    const f32x4 v1a = mfma16(ZAa.b, WvF1.b, z4);
    const f32x4 k0b = mfma16(WkF0.b, ZAb.b, z4);
    const f32x4 k1b = mfma16(WkF1.b, ZAb.b, z4);
    const f32x4 v0b = mfma16(ZAb.b, WvF0.b, z4);
    const f32x4 v1b = mfma16(ZAb.b, WvF1.b, z4);
    U8 KF0, KF1, VF0, VF1;
    KF0.u[0] = pk(k0a[0],k0a[1]); KF0.u[1] = pk(k0a[2],k0a[3]);
    KF0.u[2] = pk(k1a[0],k1a[1]); KF0.u[3] = pk(k1a[2],k1a[3]);
    KF1.u[0] = pk(k0b[0],k0b[1]); KF1.u[1] = pk(k0b[2],k0b[3]);
    KF1.u[2] = pk(k1b[0],k1b[1]); KF1.u[3] = pk(k1b[2],k1b[3]);
    VF0.u[0] = pk(v0a[0],v0a[1]); VF0.u[1] = pk(v0a[2],v0a[3]);
    VF0.u[2] = pk(v0b[0],v0b[1]); VF0.u[3] = pk(v0b[2],v0b[3]);
    VF1.u[0] = pk(v1a[0],v1a[1]); VF1.u[1] = pk(v1a[2],v1a[3]);
    VF1.u[2] = pk(v1b[0],v1b[1]); VF1.u[3] = pk(v1b[2],v1b[3]);
#pragma unroll
    for (int qt = 0; qt < 4; qt++) {
      const f32x4 S0 = mfma16(KF0.b, QB[qt].b, z4);   // keys kt+quad*4+r
      const f32x4 S1 = mfma16(KF1.b, QB[qt].b, z4);   // keys kt+16+quad*4+r
      float ps[8];
#pragma unroll
      for (int r = 0; r < 4; r++) {
        ps[r]     = exp2f(S0[r]);     // scale pre-folded into Q; no clamp needed
        ps[4 + r] = exp2f(S1[r]);
      }
      l[qt] += ((ps[0]+ps[1]) + (ps[2]+ps[3])) + ((ps[4]+ps[5]) + (ps[6]+ps[7]));
      U8 PB;
      PB.u[0] = pk(ps[0],ps[1]); PB.u[1] = pk(ps[2],ps[3]);
      PB.u[2] = pk(ps[4],ps[5]); PB.u[3] = pk(ps[6],ps[7]);
      O0[qt] = mfma16(VF0.b, PB.b, O0[qt]);
      O1[qt] = mfma16(VF1.b, PB.b, O1[qt]);
    }
  }

  // ---- epilogue: normalize, gate, out-project, LDS f32 reduce across heads ----
  // Wo A-frags are qt-invariant: load once
  U8 WoA0, WoA1;
  {
    const float4 a = *(const float4*)(Wo + col*128 + h*32 + quad*4);
    const float4 b = *(const float4*)(Wo + col*128 + h*32 + 16 + quad*4);
    WoA0.u[0] = pk(a.x,a.y); WoA0.u[1] = pk(a.z,a.w);
    WoA0.u[2] = pk(b.x,b.y); WoA0.u[3] = pk(b.z,b.w);
    const float4 c = *(const float4*)(Wo + (16 + col)*128 + h*32 + quad*4);
    const float4 d = *(const float4*)(Wo + (16 + col)*128 + h*32 + 16 + quad*4);
    WoA1.u[0] = pk(c.x,c.y); WoA1.u[1] = pk(c.z,c.w);
    WoA1.u[2] = pk(d.x,d.y); WoA1.u[3] = pk(d.z,d.w);
  }
#pragma unroll
  for (int qt = 0; qt < 4; qt++) {
    float lv = l[qt];
    lv += __shfl_xor(lv, 16);   // reduce over quads (keys spread reg-dim x quad)
    lv += __shfl_xor(lv, 32);
    const float inv = 1.f / lv;
    float og[8];
#pragma unroll
    for (int r = 0; r < 4; r++) {
      og[r]     = O0[qt][r] * inv * G[qt][r];
      og[4 + r] = O1[qt][r] * inv * G[qt][4 + r];
    }
    U8 OB;   // gated O^T as permuted-k B-frag (k-permutation matches WoA)
    OB.u[0] = pk(og[0],og[1]); OB.u[1] = pk(og[2],og[3]);
    OB.u[2] = pk(og[4],og[5]); OB.u[3] = pk(og[6],og[7]);
    const f32x4 p0 = mfma16(WoA0.b, OB.b, z4);   // couts 0..15, q=col
    const f32x4 p1 = mfma16(WoA1.b, OB.b, z4);   // couts 16..31
    const int q = qt*16 + col;
#pragma unroll
    for (int r = 0; r < 4; r++) {
      atomicAdd(&sO[q][quad*4 + r],      p0[r]);   // ds_add_f32, ~2-way banks (pad 33)
      atomicAdd(&sO[q][16 + quad*4 + r], p1[r]);
    }
  }
  __syncthreads();   // barrier 2 of 2

  // ---------------- store: 64 q x 32 ch, bo already folded into sO ----------------
  {
    const int q  = tid >> 2;
    const int c0 = (tid & 3) * 8;
    float* op = out + (((i << 8) + qq*64 + q) << 5) + c0;
    const float4 A = make_float4(sO[q][c0+0], sO[q][c0+1], sO[q][c0+2], sO[q][c0+3]);
    const float4 B = make_float4(sO[q][c0+4], sO[q][c0+5], sO[q][c0+6], sO[q][c0+7]);
    *(float4*)op       = A;
    *(float4*)(op + 4) = B;
  }
}

extern "C" void kernel_launch(void* const* d_in, const int* in_sizes, int n_in,
                              void* d_out, int out_size, void* d_ws, size_t ws_size,
                              hipStream_t stream)
{
  const float* z    = (const float*)d_in[0];
  const float* ln_g = (const float*)d_in[1];
  const float* ln_b = (const float*)d_in[2];
  const float* Wq   = (const float*)d_in[3];
  const float* Wk   = (const float*)d_in[4];
  const float* Wv   = (const float*)d_in[5];
  // d_in[6] = Wb: softmax shift invariance -> exactly cancels, unused.
  const float* Wg   = (const float*)d_in[7];
  const float* bg   = (const float*)d_in[8];
  const float* Wo   = (const float*)d_in[9];
  const float* bo   = (const float*)d_in[10];

  tri_attn_fused<<<dim3(4, 256), 256, 0, stream>>>(z, ln_g, ln_b, Wq, Wk, Wv, Wg, bg, Wo, bo,
                                                   (float*)d_out);
}

// Round 2
// 155.758 us; speedup vs baseline: 1.0027x; 1.0027x over previous
//
#include <hip/hip_runtime.h>

// TriangleAttentionStartingNode — MI355X gfx950. f32 global I/O, bf16 MFMA compute.
//
// R6: spill-fix round. R5 counters showed launch_bounds(256,3) forced VGPR=84
// -> ~40 regs/thread spilled to scratch (WRITE_SIZE 51 MB vs 8.4 MB output,
// FETCH +spill reloads, VALUBusy 31%). Fix: shrink honest register demand
// below the 128-reg / 4-waves-per-SIMD boundary and bound to (256,4):
//   (a) gates G[4][8] (32 f32 regs) evicted from loop-carried state —
//       recomputed in the epilogue via 2 MFMAs/qt against the intact sZ
//       (bit-identical math, Wg frags + bg loaded post-loop);
//   (b) sched_barrier(0) after the k-loop so epilogue weight loads (Wo/Wg/bg)
//       are not hoisted into the loop;
//   (c) loop-carried state now QB(16)+O(32)+l(4)+WkF/WvF(16) ~= 68 regs.
//
// Structure from R5 (kept): wave == head; K/V projection fused into the
// attention k-loop, K/V fragments register-resident (lane-identical to the
// R4 sK/sVt round-trip, so bit-identical math); no per-head barriers
// (2 barriers total); cross-head out reduction via f32 ds_add into sO
// (bo folded into init); grid 4x256 (64 q/block).
//
// Kept from R4: v_perm round-half-up bf16 packing; softmax scale*log2e folded
// into Q; no exp clamp (post-LN scores O(1)); Wb unused (softmax shift
// invariance); tree-reduced l with 2 shfl_xor.

typedef unsigned short u16;
typedef unsigned int   u32;
typedef __bf16 bf16x8 __attribute__((ext_vector_type(8)));
typedef float  f32x4  __attribute__((ext_vector_type(4)));

union U8 { bf16x8 b; u32 u[4]; };

// round-half-up f32->bf16 pair pack: 2 adds + 1 v_perm
__device__ __forceinline__ u32 pk(float a, float b) {
  const u32 au = __float_as_uint(a) + 0x8000u;
  const u32 bu = __float_as_uint(b) + 0x8000u;
  return __builtin_amdgcn_perm(bu, au, 0x07060302u);  // {b.hi16, a.hi16}
}
__device__ __forceinline__ f32x4 mfma16(bf16x8 a, bf16x8 b, f32x4 c) {
  return __builtin_amdgcn_mfma_f32_16x16x32_bf16(a, b, c, 0, 0, 0);
}

#define LDZ 40    // 80 B rows (16B-aligned for uint4 reads)

__global__ __launch_bounds__(256, 4) void tri_attn_fused(
    const float* __restrict__ z,  const float* __restrict__ ln_g, const float* __restrict__ ln_b,
    const float* __restrict__ Wq, const float* __restrict__ Wk,   const float* __restrict__ Wv,
    const float* __restrict__ Wg, const float* __restrict__ bg,
    const float* __restrict__ Wo, const float* __restrict__ bo,   float* __restrict__ out)
{
  __shared__ u16   sZ[256][LDZ];   // zn[pos][ch] bf16, all 256 positions of row i (20480 B)
  __shared__ float sO[64][33];     // f32 cross-head out reduction, +1 pad (8448 B)

  const int qq   = blockIdx.x;     // q-quarter: queries qq*64 .. qq*64+63
  const int i    = blockIdx.y;
  const int tid  = threadIdx.x;
  const int h    = tid >> 6;       // wave == head
  const int lane = tid & 63, quad = lane >> 4, col = lane & 15;
  const f32x4 z4 = {0.f, 0.f, 0.f, 0.f};

  // ---------------- phase 0: LayerNorm -> sZ; init sO = bo ----------------
  {
    const float* zr = z + (((i << 8) + tid) << 5);
    float x[32];
#pragma unroll
    for (int e = 0; e < 8; e++) {
      const float4 v = *(const float4*)(zr + e*4);
      x[4*e] = v.x; x[4*e+1] = v.y; x[4*e+2] = v.z; x[4*e+3] = v.w;
    }
    float mu = 0.f;
#pragma unroll
    for (int c = 0; c < 32; c++) mu += x[c];
    mu *= (1.f / 32.f);
    float s2 = 0.f;
#pragma unroll
    for (int c = 0; c < 32; c++) { float d = x[c] - mu; s2 += d * d; }
    const float rstd = rsqrtf(s2 * (1.f / 32.f) + 1e-5f);
    u32* dst = (u32*)&sZ[tid][0];
#pragma unroll
    for (int e = 0; e < 16; e++) {
      const float za = (x[2*e]   - mu) * rstd * ln_g[2*e]   + ln_b[2*e];
      const float zb = (x[2*e+1] - mu) * rstd * ln_g[2*e+1] + ln_b[2*e+1];
      dst[e] = pk(za, zb);
    }
    // sO init: bo broadcast into every q-row (pad col -> 0)
    float* p = &sO[0][0];
    for (int idx = tid; idx < 64*33; idx += 256) {
      const int c = idx % 33;
      p[idx] = (c < 32) ? bo[c] : 0.f;
    }
  }
  __syncthreads();   // barrier 1 of 2

  // per-head weight fragment loader (f32 -> bf16 pack), L1/L2-hot
  auto ldw = [&](const float* W, int cb) -> U8 {
    const float* p = W + h*1024 + (cb*16 + col)*32 + quad*8;
    const float4 a = *(const float4*)(p);
    const float4 b = *(const float4*)(p + 4);
    U8 t;
    t.u[0] = pk(a.x, a.y); t.u[1] = pk(a.z, a.w);
    t.u[2] = pk(b.x, b.y); t.u[3] = pk(b.z, b.w);
    return t;
  };

  // ---------------- Q for this wave's 4 q-tiles (gates deferred to epilogue) --------
  U8 QB[4];          // Q (pre-scaled by (1/sqrt32)*log2e) permuted-k B-frags
  {
    const U8 WqF0 = ldw(Wq,0), WqF1 = ldw(Wq,1);
    const float k2e = 0.17677669529663687f * 1.44269504089f;
#pragma unroll
    for (int qt = 0; qt < 4; qt++) {
      const int row = (qq*4 + qt)*16 + col;
      U8 ZA;
      {
        const uint4 v = *(const uint4*)&sZ[row][quad*8];
        ZA.u[0] = v.x; ZA.u[1] = v.y; ZA.u[2] = v.z; ZA.u[3] = v.w;
      }
      const f32x4 q0 = mfma16(WqF0.b, ZA.b, z4);
      const f32x4 q1 = mfma16(WqF1.b, ZA.b, z4);
      QB[qt].u[0] = pk(q0[0]*k2e, q0[1]*k2e); QB[qt].u[1] = pk(q0[2]*k2e, q0[3]*k2e);
      QB[qt].u[2] = pk(q1[0]*k2e, q1[1]*k2e); QB[qt].u[3] = pk(q1[2]*k2e, q1[3]*k2e);
    }
  }

  // -------- fused K/V projection + flash attention over all 256 keys --------
  const U8 WkF0 = ldw(Wk,0), WkF1 = ldw(Wk,1);
  const U8 WvF0 = ldw(Wv,0), WvF1 = ldw(Wv,1);
  f32x4 O0[4] = {z4, z4, z4, z4};   // O^T: ch=quad*4+r, q=col
  f32x4 O1[4] = {z4, z4, z4, z4};   // O^T: ch=16+quad*4+r
  float l[4]  = {0.f, 0.f, 0.f, 0.f};

#pragma unroll
  for (int kt = 0; kt < 256; kt += 32) {
    // project K,V for key-tiles kt and kt+16 (register-resident fragments;
    // packs are bit-identical to R4's sK/sVt store->load round trip)
    U8 ZAa, ZAb;
    {
      const uint4 va = *(const uint4*)&sZ[kt + col][quad*8];
      ZAa.u[0] = va.x; ZAa.u[1] = va.y; ZAa.u[2] = va.z; ZAa.u[3] = va.w;
      const uint4 vb = *(const uint4*)&sZ[kt + 16 + col][quad*8];
      ZAb.u[0] = vb.x; ZAb.u[1] = vb.y; ZAb.u[2] = vb.z; ZAb.u[3] = vb.w;
    }
    U8 KF0, KF1, VF0, VF1;
    {
      const f32x4 k0a = mfma16(WkF0.b, ZAa.b, z4);   // K^T: ch=quad*4+r, key=kt+col
      const f32x4 k1a = mfma16(WkF1.b, ZAa.b, z4);
      KF0.u[0] = pk(k0a[0],k0a[1]); KF0.u[1] = pk(k0a[2],k0a[3]);
      KF0.u[2] = pk(k1a[0],k1a[1]); KF0.u[3] = pk(k1a[2],k1a[3]);
      const f32x4 k0b = mfma16(WkF0.b, ZAb.b, z4);
      const f32x4 k1b = mfma16(WkF1.b, ZAb.b, z4);
      KF1.u[0] = pk(k0b[0],k0b[1]); KF1.u[1] = pk(k0b[2],k0b[3]);
      KF1.u[2] = pk(k1b[0],k1b[1]); KF1.u[3] = pk(k1b[2],k1b[3]);
      const f32x4 v0a = mfma16(ZAa.b, WvF0.b, z4);   // V: key=kt+quad*4+r, ch=col
      const f32x4 v0b = mfma16(ZAb.b, WvF0.b, z4);
      VF0.u[0] = pk(v0a[0],v0a[1]); VF0.u[1] = pk(v0a[2],v0a[3]);
      VF0.u[2] = pk(v0b[0],v0b[1]); VF0.u[3] = pk(v0b[2],v0b[3]);
      const f32x4 v1a = mfma16(ZAa.b, WvF1.b, z4);
      const f32x4 v1b = mfma16(ZAb.b, WvF1.b, z4);
      VF1.u[0] = pk(v1a[0],v1a[1]); VF1.u[1] = pk(v1a[2],v1a[3]);
      VF1.u[2] = pk(v1b[0],v1b[1]); VF1.u[3] = pk(v1b[2],v1b[3]);
    }
#pragma unroll
    for (int qt = 0; qt < 4; qt++) {
      const f32x4 S0 = mfma16(KF0.b, QB[qt].b, z4);   // keys kt+quad*4+r
      const f32x4 S1 = mfma16(KF1.b, QB[qt].b, z4);   // keys kt+16+quad*4+r
      float ps[8];
#pragma unroll
      for (int r = 0; r < 4; r++) {
        ps[r]     = exp2f(S0[r]);     // scale pre-folded into Q; no clamp needed
        ps[4 + r] = exp2f(S1[r]);
      }
      l[qt] += ((ps[0]+ps[1]) + (ps[2]+ps[3])) + ((ps[4]+ps[5]) + (ps[6]+ps[7]));
      U8 PB;
      PB.u[0] = pk(ps[0],ps[1]); PB.u[1] = pk(ps[2],ps[3]);
      PB.u[2] = pk(ps[4],ps[5]); PB.u[3] = pk(ps[6],ps[7]);
      O0[qt] = mfma16(VF0.b, PB.b, O0[qt]);
      O1[qt] = mfma16(VF1.b, PB.b, O1[qt]);
    }
  }

  // keep epilogue loads (Wg/Wo/bg) out of the k-loop's register live-range
  __builtin_amdgcn_sched_barrier(0);

  // ---- epilogue: recompute gates, normalize, out-project, LDS f32 reduce ----
  const U8 WgF0 = ldw(Wg,0), WgF1 = ldw(Wg,1);
  float bgl[8];
#pragma unroll
  for (int r = 0; r < 4; r++) {
    bgl[r]     = bg[h*32 + quad*4 + r];
    bgl[4 + r] = bg[h*32 + 16 + quad*4 + r];
  }
  // Wo A-frags are qt-invariant: load once (k-permutation matches OB below)
  U8 WoA0, WoA1;
  {
    const float4 a = *(const float4*)(Wo + col*128 + h*32 + quad*4);
    const float4 b = *(const float4*)(Wo + col*128 + h*32 + 16 + quad*4);
    WoA0.u[0] = pk(a.x,a.y); WoA0.u[1] = pk(a.z,a.w);
    WoA0.u[2] = pk(b.x,b.y); WoA0.u[3] = pk(b.z,b.w);
    const float4 c = *(const float4*)(Wo + (16 + col)*128 + h*32 + quad*4);
    const float4 d = *(const float4*)(Wo + (16 + col)*128 + h*32 + 16 + quad*4);
    WoA1.u[0] = pk(c.x,c.y); WoA1.u[1] = pk(c.z,c.w);
    WoA1.u[2] = pk(d.x,d.y); WoA1.u[3] = pk(d.z,d.w);
  }
#pragma unroll
  for (int qt = 0; qt < 4; qt++) {
    const int row = (qq*4 + qt)*16 + col;
    U8 ZA;
    {
      const uint4 v = *(const uint4*)&sZ[row][quad*8];
      ZA.u[0] = v.x; ZA.u[1] = v.y; ZA.u[2] = v.z; ZA.u[3] = v.w;
    }
    const f32x4 g0 = mfma16(WgF0.b, ZA.b, z4);   // gate pre-sigmoid: ch=quad*4+r, q=col
    const f32x4 g1 = mfma16(WgF1.b, ZA.b, z4);
    float lv = l[qt];
    lv += __shfl_xor(lv, 16);   // reduce over quads (keys spread reg-dim x quad)
    lv += __shfl_xor(lv, 32);
    const float inv = 1.f / lv;
    float og[8];
#pragma unroll
    for (int r = 0; r < 4; r++) {
      og[r]     = O0[qt][r] * inv * (1.f / (1.f + __expf(-(g0[r] + bgl[r]))));
      og[4 + r] = O1[qt][r] * inv * (1.f / (1.f + __expf(-(g1[r] + bgl[4 + r]))));
    }
    U8 OB;   // gated O^T as permuted-k B-frag (k-permutation matches WoA)
    OB.u[0] = pk(og[0],og[1]); OB.u[1] = pk(og[2],og[3]);
    OB.u[2] = pk(og[4],og[5]); OB.u[3] = pk(og[6],og[7]);
    const f32x4 p0 = mfma16(WoA0.b, OB.b, z4);   // couts 0..15, q=col
    const f32x4 p1 = mfma16(WoA1.b, OB.b, z4);   // couts 16..31
    const int q = qt*16 + col;
#pragma unroll
    for (int r = 0; r < 4; r++) {
      atomicAdd(&sO[q][quad*4 + r],      p0[r]);   // ds_add_f32, pad-33 banks
      atomicAdd(&sO[q][16 + quad*4 + r], p1[r]);
    }
  }
  __syncthreads();   // barrier 2 of 2

  // ---------------- store: 64 q x 32 ch, bo already folded into sO ----------------
  {
    const int q  = tid >> 2;
    const int c0 = (tid & 3) * 8;
    float* op = out + (((i << 8) + qq*64 + q) << 5) + c0;
    const float4 A = make_float4(sO[q][c0+0], sO[q][c0+1], sO[q][c0+2], sO[q][c0+3]);
    const float4 B = make_float4(sO[q][c0+4], sO[q][c0+5], sO[q][c0+6], sO[q][c0+7]);
    *(float4*)op       = A;
    *(float4*)(op + 4) = B;
  }
}

extern "C" void kernel_launch(void* const* d_in, const int* in_sizes, int n_in,
                              void* d_out, int out_size, void* d_ws, size_t ws_size,
                              hipStream_t stream)
{
  const float* z    = (const float*)d_in[0];
  const float* ln_g = (const float*)d_in[1];
  const float* ln_b = (const float*)d_in[2];
  const float* Wq   = (const float*)d_in[3];
  const float* Wk   = (const float*)d_in[4];
  const float* Wv   = (const float*)d_in[5];
  // d_in[6] = Wb: softmax shift invariance -> exactly cancels, unused.
  const float* Wg   = (const float*)d_in[7];
  const float* bg   = (const float*)d_in[8];
  const float* Wo   = (const float*)d_in[9];
  const float* bo   = (const float*)d_in[10];

  tri_attn_fused<<<dim3(4, 256), 256, 0, stream>>>(z, ln_g, ln_b, Wq, Wk, Wv, Wg, bg, Wo, bo,
                                                   (float*)d_out);
}

// Round 3
// 147.275 us; speedup vs baseline: 1.0605x; 1.0576x over previous
//
#include <hip/hip_runtime.h>

// TriangleAttentionStartingNode — MI355X gfx950. f32 global I/O, bf16 MFMA compute.
//
// R7: launch-bounds A/B fix. Cross-round evidence isolated the regression to
// the 2nd __launch_bounds__ arg: (256)->VGPR 116 clean (R4); (256,3)->84 +
// 51 MB scratch (R5); (256,4)->64 + 90 MB scratch (R6). The allocator
// over-restricts below the budget the bound implies and spills ~50 regs.
// R7 = R6 with plain __launch_bounds__(256): honest demand ~110-120 regs
// fits the 128-reg / 4-waves-per-SIMD step naturally; LDS 29.2 KB allows
// 5 blocks/CU -> occupancy should land at 4 blocks/CU (50%).
//
// Structure (R5/R6): wave == head; K/V projection fused into the attention
// k-loop, K/V fragments register-resident (lane-identical to the R4 sK/sVt
// round-trip, so bit-identical math); gates recomputed in epilogue (not
// loop-carried); 2 barriers total; cross-head out reduction via f32 ds_add
// into sO (bo folded into init); grid 4x256 (64 q/block).
//
// Kept from R4: v_perm round-half-up bf16 packing; softmax scale*log2e folded
// into Q; no exp clamp (post-LN scores O(1)); Wb unused (softmax shift
// invariance); tree-reduced l with 2 shfl_xor.

typedef unsigned short u16;
typedef unsigned int   u32;
typedef __bf16 bf16x8 __attribute__((ext_vector_type(8)));
typedef float  f32x4  __attribute__((ext_vector_type(4)));

union U8 { bf16x8 b; u32 u[4]; };

// round-half-up f32->bf16 pair pack: 2 adds + 1 v_perm
__device__ __forceinline__ u32 pk(float a, float b) {
  const u32 au = __float_as_uint(a) + 0x8000u;
  const u32 bu = __float_as_uint(b) + 0x8000u;
  return __builtin_amdgcn_perm(bu, au, 0x07060302u);  // {b.hi16, a.hi16}
}
__device__ __forceinline__ f32x4 mfma16(bf16x8 a, bf16x8 b, f32x4 c) {
  return __builtin_amdgcn_mfma_f32_16x16x32_bf16(a, b, c, 0, 0, 0);
}

#define LDZ 40    // 80 B rows (16B-aligned for uint4 reads)

__global__ __launch_bounds__(256) void tri_attn_fused(
    const float* __restrict__ z,  const float* __restrict__ ln_g, const float* __restrict__ ln_b,
    const float* __restrict__ Wq, const float* __restrict__ Wk,   const float* __restrict__ Wv,
    const float* __restrict__ Wg, const float* __restrict__ bg,
    const float* __restrict__ Wo, const float* __restrict__ bo,   float* __restrict__ out)
{
  __shared__ u16   sZ[256][LDZ];   // zn[pos][ch] bf16, all 256 positions of row i (20480 B)
  __shared__ float sO[64][33];     // f32 cross-head out reduction, +1 pad (8448 B)

  const int qq   = blockIdx.x;     // q-quarter: queries qq*64 .. qq*64+63
  const int i    = blockIdx.y;
  const int tid  = threadIdx.x;
  const int h    = tid >> 6;       // wave == head
  const int lane = tid & 63, quad = lane >> 4, col = lane & 15;
  const f32x4 z4 = {0.f, 0.f, 0.f, 0.f};

  // ---------------- phase 0: LayerNorm -> sZ; init sO = bo ----------------
  {
    const float* zr = z + (((i << 8) + tid) << 5);
    float x[32];
#pragma unroll
    for (int e = 0; e < 8; e++) {
      const float4 v = *(const float4*)(zr + e*4);
      x[4*e] = v.x; x[4*e+1] = v.y; x[4*e+2] = v.z; x[4*e+3] = v.w;
    }
    float mu = 0.f;
#pragma unroll
    for (int c = 0; c < 32; c++) mu += x[c];
    mu *= (1.f / 32.f);
    float s2 = 0.f;
#pragma unroll
    for (int c = 0; c < 32; c++) { float d = x[c] - mu; s2 += d * d; }
    const float rstd = rsqrtf(s2 * (1.f / 32.f) + 1e-5f);
    u32* dst = (u32*)&sZ[tid][0];
#pragma unroll
    for (int e = 0; e < 16; e++) {
      const float za = (x[2*e]   - mu) * rstd * ln_g[2*e]   + ln_b[2*e];
      const float zb = (x[2*e+1] - mu) * rstd * ln_g[2*e+1] + ln_b[2*e+1];
      dst[e] = pk(za, zb);
    }
    // sO init: bo broadcast into every q-row (pad col -> 0)
    float* p = &sO[0][0];
    for (int idx = tid; idx < 64*33; idx += 256) {
      const int c = idx % 33;
      p[idx] = (c < 32) ? bo[c] : 0.f;
    }
  }
  __syncthreads();   // barrier 1 of 2

  // per-head weight fragment loader (f32 -> bf16 pack), L1/L2-hot
  auto ldw = [&](const float* W, int cb) -> U8 {
    const float* p = W + h*1024 + (cb*16 + col)*32 + quad*8;
    const float4 a = *(const float4*)(p);
    const float4 b = *(const float4*)(p + 4);
    U8 t;
    t.u[0] = pk(a.x, a.y); t.u[1] = pk(a.z, a.w);
    t.u[2] = pk(b.x, b.y); t.u[3] = pk(b.z, b.w);
    return t;
  };

  // ---------------- Q for this wave's 4 q-tiles (gates deferred to epilogue) --------
  U8 QB[4];          // Q (pre-scaled by (1/sqrt32)*log2e) permuted-k B-frags
  {
    const U8 WqF0 = ldw(Wq,0), WqF1 = ldw(Wq,1);
    const float k2e = 0.17677669529663687f * 1.44269504089f;
#pragma unroll
    for (int qt = 0; qt < 4; qt++) {
      const int row = (qq*4 + qt)*16 + col;
      U8 ZA;
      {
        const uint4 v = *(const uint4*)&sZ[row][quad*8];
        ZA.u[0] = v.x; ZA.u[1] = v.y; ZA.u[2] = v.z; ZA.u[3] = v.w;
      }
      const f32x4 q0 = mfma16(WqF0.b, ZA.b, z4);
      const f32x4 q1 = mfma16(WqF1.b, ZA.b, z4);
      QB[qt].u[0] = pk(q0[0]*k2e, q0[1]*k2e); QB[qt].u[1] = pk(q0[2]*k2e, q0[3]*k2e);
      QB[qt].u[2] = pk(q1[0]*k2e, q1[1]*k2e); QB[qt].u[3] = pk(q1[2]*k2e, q1[3]*k2e);
    }
  }

  // -------- fused K/V projection + flash attention over all 256 keys --------
  const U8 WkF0 = ldw(Wk,0), WkF1 = ldw(Wk,1);
  const U8 WvF0 = ldw(Wv,0), WvF1 = ldw(Wv,1);
  f32x4 O0[4] = {z4, z4, z4, z4};   // O^T: ch=quad*4+r, q=col
  f32x4 O1[4] = {z4, z4, z4, z4};   // O^T: ch=16+quad*4+r
  float l[4]  = {0.f, 0.f, 0.f, 0.f};

#pragma unroll
  for (int kt = 0; kt < 256; kt += 32) {
    // project K,V for key-tiles kt and kt+16 (register-resident fragments;
    // packs are bit-identical to R4's sK/sVt store->load round trip)
    U8 ZAa, ZAb;
    {
      const uint4 va = *(const uint4*)&sZ[kt + col][quad*8];
      ZAa.u[0] = va.x; ZAa.u[1] = va.y; ZAa.u[2] = va.z; ZAa.u[3] = va.w;
      const uint4 vb = *(const uint4*)&sZ[kt + 16 + col][quad*8];
      ZAb.u[0] = vb.x; ZAb.u[1] = vb.y; ZAb.u[2] = vb.z; ZAb.u[3] = vb.w;
    }
    U8 KF0, KF1, VF0, VF1;
    {
      const f32x4 k0a = mfma16(WkF0.b, ZAa.b, z4);   // K^T: ch=quad*4+r, key=kt+col
      const f32x4 k1a = mfma16(WkF1.b, ZAa.b, z4);
      KF0.u[0] = pk(k0a[0],k0a[1]); KF0.u[1] = pk(k0a[2],k0a[3]);
      KF0.u[2] = pk(k1a[0],k1a[1]); KF0.u[3] = pk(k1a[2],k1a[3]);
      const f32x4 k0b = mfma16(WkF0.b, ZAb.b, z4);
      const f32x4 k1b = mfma16(WkF1.b, ZAb.b, z4);
      KF1.u[0] = pk(k0b[0],k0b[1]); KF1.u[1] = pk(k0b[2],k0b[3]);
      KF1.u[2] = pk(k1b[0],k1b[1]); KF1.u[3] = pk(k1b[2],k1b[3]);
      const f32x4 v0a = mfma16(ZAa.b, WvF0.b, z4);   // V: key=kt+quad*4+r, ch=col
      const f32x4 v0b = mfma16(ZAb.b, WvF0.b, z4);
      VF0.u[0] = pk(v0a[0],v0a[1]); VF0.u[1] = pk(v0a[2],v0a[3]);
      VF0.u[2] = pk(v0b[0],v0b[1]); VF0.u[3] = pk(v0b[2],v0b[3]);
      const f32x4 v1a = mfma16(ZAa.b, WvF1.b, z4);
      const f32x4 v1b = mfma16(ZAb.b, WvF1.b, z4);
      VF1.u[0] = pk(v1a[0],v1a[1]); VF1.u[1] = pk(v1a[2],v1a[3]);
      VF1.u[2] = pk(v1b[0],v1b[1]); VF1.u[3] = pk(v1b[2],v1b[3]);
    }
#pragma unroll
    for (int qt = 0; qt < 4; qt++) {
      const f32x4 S0 = mfma16(KF0.b, QB[qt].b, z4);   // keys kt+quad*4+r
      const f32x4 S1 = mfma16(KF1.b, QB[qt].b, z4);   // keys kt+16+quad*4+r
      float ps[8];
#pragma unroll
      for (int r = 0; r < 4; r++) {
        ps[r]     = exp2f(S0[r]);     // scale pre-folded into Q; no clamp needed
        ps[4 + r] = exp2f(S1[r]);
      }
      l[qt] += ((ps[0]+ps[1]) + (ps[2]+ps[3])) + ((ps[4]+ps[5]) + (ps[6]+ps[7]));
      U8 PB;
      PB.u[0] = pk(ps[0],ps[1]); PB.u[1] = pk(ps[2],ps[3]);
      PB.u[2] = pk(ps[4],ps[5]); PB.u[3] = pk(ps[6],ps[7]);
      O0[qt] = mfma16(VF0.b, PB.b, O0[qt]);
      O1[qt] = mfma16(VF1.b, PB.b, O1[qt]);
    }
  }

  // keep epilogue loads (Wg/Wo/bg) out of the k-loop's register live-range
  __builtin_amdgcn_sched_barrier(0);

  // ---- epilogue: recompute gates, normalize, out-project, LDS f32 reduce ----
  const U8 WgF0 = ldw(Wg,0), WgF1 = ldw(Wg,1);
  float bgl[8];
#pragma unroll
  for (int r = 0; r < 4; r++) {
    bgl[r]     = bg[h*32 + quad*4 + r];
    bgl[4 + r] = bg[h*32 + 16 + quad*4 + r];
  }
  // Wo A-frags are qt-invariant: load once (k-permutation matches OB below)
  U8 WoA0, WoA1;
  {
    const float4 a = *(const float4*)(Wo + col*128 + h*32 + quad*4);
    const float4 b = *(const float4*)(Wo + col*128 + h*32 + 16 + quad*4);
    WoA0.u[0] = pk(a.x,a.y); WoA0.u[1] = pk(a.z,a.w);
    WoA0.u[2] = pk(b.x,b.y); WoA0.u[3] = pk(b.z,b.w);
    const float4 c = *(const float4*)(Wo + (16 + col)*128 + h*32 + quad*4);
    const float4 d = *(const float4*)(Wo + (16 + col)*128 + h*32 + 16 + quad*4);
    WoA1.u[0] = pk(c.x,c.y); WoA1.u[1] = pk(c.z,c.w);
    WoA1.u[2] = pk(d.x,d.y); WoA1.u[3] = pk(d.z,d.w);
  }
#pragma unroll
  for (int qt = 0; qt < 4; qt++) {
    const int row = (qq*4 + qt)*16 + col;
    U8 ZA;
    {
      const uint4 v = *(const uint4*)&sZ[row][quad*8];
      ZA.u[0] = v.x; ZA.u[1] = v.y; ZA.u[2] = v.z; ZA.u[3] = v.w;
    }
    const f32x4 g0 = mfma16(WgF0.b, ZA.b, z4);   // gate pre-sigmoid: ch=quad*4+r, q=col
    const f32x4 g1 = mfma16(WgF1.b, ZA.b, z4);
    float lv = l[qt];
    lv += __shfl_xor(lv, 16);   // reduce over quads (keys spread reg-dim x quad)
    lv += __shfl_xor(lv, 32);
    const float inv = 1.f / lv;
    float og[8];
#pragma unroll
    for (int r = 0; r < 4; r++) {
      og[r]     = O0[qt][r] * inv * (1.f / (1.f + __expf(-(g0[r] + bgl[r]))));
      og[4 + r] = O1[qt][r] * inv * (1.f / (1.f + __expf(-(g1[r] + bgl[4 + r]))));
    }
    U8 OB;   // gated O^T as permuted-k B-frag (k-permutation matches WoA)
    OB.u[0] = pk(og[0],og[1]); OB.u[1] = pk(og[2],og[3]);
    OB.u[2] = pk(og[4],og[5]); OB.u[3] = pk(og[6],og[7]);
    const f32x4 p0 = mfma16(WoA0.b, OB.b, z4);   // couts 0..15, q=col
    const f32x4 p1 = mfma16(WoA1.b, OB.b, z4);   // couts 16..31
    const int q = qt*16 + col;
#pragma unroll
    for (int r = 0; r < 4; r++) {
      atomicAdd(&sO[q][quad*4 + r],      p0[r]);   // ds_add_f32, pad-33 banks
      atomicAdd(&sO[q][16 + quad*4 + r], p1[r]);
    }
  }
  __syncthreads();   // barrier 2 of 2

  // ---------------- store: 64 q x 32 ch, bo already folded into sO ----------------
  {
    const int q  = tid >> 2;
    const int c0 = (tid & 3) * 8;
    float* op = out + (((i << 8) + qq*64 + q) << 5) + c0;
    const float4 A = make_float4(sO[q][c0+0], sO[q][c0+1], sO[q][c0+2], sO[q][c0+3]);
    const float4 B = make_float4(sO[q][c0+4], sO[q][c0+5], sO[q][c0+6], sO[q][c0+7]);
    *(float4*)op       = A;
    *(float4*)(op + 4) = B;
  }
}

extern "C" void kernel_launch(void* const* d_in, const int* in_sizes, int n_in,
                              void* d_out, int out_size, void* d_ws, size_t ws_size,
                              hipStream_t stream)
{
  const float* z    = (const float*)d_in[0];
  const float* ln_g = (const float*)d_in[1];
  const float* ln_b = (const float*)d_in[2];
  const float* Wq   = (const float*)d_in[3];
  const float* Wk   = (const float*)d_in[4];
  const float* Wv   = (const float*)d_in[5];
  // d_in[6] = Wb: softmax shift invariance -> exactly cancels, unused.
  const float* Wg   = (const float*)d_in[7];
  const float* bg   = (const float*)d_in[8];
  const float* Wo   = (const float*)d_in[9];
  const float* bo   = (const float*)d_in[10];

  tri_attn_fused<<<dim3(4, 256), 256, 0, stream>>>(z, ln_g, ln_b, Wq, Wk, Wv, Wg, bg, Wo, bo,
                                                   (float*)d_out);
}

// Round 4
// 120.564 us; speedup vs baseline: 1.2954x; 1.2216x over previous
//
#include <hip/hip_runtime.h>

// TriangleAttentionStartingNode — MI355X gfx950. f32 global I/O, bf16 MFMA compute.
//
// R8: revert to the R4 structure (proven 54 µs/dispatch; the R5-R7 wave=head
// register-resident-K/V branch measured 80 µs clean — serialized the
// producer->consumer chain per wave and 2x'd K/V FLOPs; closed) and fix R4's
// actual limiter: LDS-capped residency. R4's 55.8 KB -> 2 blocks/CU, occ 18%.
// Change: split-K staging — K/V projected and consumed in two 128-key halves
// per head, halving sK (256->128 rows) and sVt (260->132 cols):
// LDS 55.8 -> 38.1 KB -> 4 blocks/CU. Q/G moved to a per-head pre-phase
// (must precede half-0 attention for qhalf=1 blocks). l/O accumulate across
// halves in the same ascending kb order -> bit-identical results to R4.
// Barriers 9 -> 17, amortized by doubled block residency.
// Plain __launch_bounds__(256): the 2nd arg caused 50-reg spills (R5/R6).
//
// Kept from R4: grid (qhalf=2, i=256), 256 thr; v_perm round-half-up bf16
// packing; softmax scale*log2e folded into Q; no exp clamp (post-LN scores
// O(1)); Wb unused (softmax shift invariance); tree-reduced l.

typedef unsigned short u16;
typedef unsigned int   u32;
typedef __bf16 bf16x8 __attribute__((ext_vector_type(8)));
typedef float  f32x4  __attribute__((ext_vector_type(4)));

union U8 { bf16x8 b; u32 u[4]; };

// round-half-up f32->bf16 pair pack: 2 adds + 1 v_perm
__device__ __forceinline__ u32 pk(float a, float b) {
  const u32 au = __float_as_uint(a) + 0x8000u;
  const u32 bu = __float_as_uint(b) + 0x8000u;
  return __builtin_amdgcn_perm(bu, au, 0x07060302u);  // {b.hi16, a.hi16}
}
__device__ __forceinline__ f32x4 mfma16(bf16x8 a, bf16x8 b, f32x4 c) {
  return __builtin_amdgcn_mfma_f32_16x16x32_bf16(a, b, c, 0, 0, 0);
}

#define LDZ 40    // 80 B rows (16B-aligned uint4 reads)
#define LDK 36    // 72 B rows (same bank stride mod 32 as R4)
#define LDV 132   // 264 B rows (same bank stride mod 32 as R4's 260)

__global__ __launch_bounds__(256) void tri_attn_fused(
    const float* __restrict__ z,  const float* __restrict__ ln_g, const float* __restrict__ ln_b,
    const float* __restrict__ Wq, const float* __restrict__ Wk,   const float* __restrict__ Wv,
    const float* __restrict__ Wg, const float* __restrict__ bg,
    const float* __restrict__ Wo, const float* __restrict__ bo,   float* __restrict__ out)
{
  __shared__ u16 sZ [256][LDZ];   // zn[pos][ch]   bf16               20480 B
  __shared__ u16 sK [128][LDK];   // K[key%128][ch] bf16 (per half)    9216 B
  __shared__ u16 sVt[32][LDV];    // V^T[ch][key%128] bf16 (per half)  8448 B

  const int qhalf = blockIdx.x;
  const int i     = blockIdx.y;
  const int tid   = threadIdx.x;
  const int wave  = tid >> 6, lane = tid & 63, quad = lane >> 4, col = lane & 15;
  const f32x4 z4  = {0.f, 0.f, 0.f, 0.f};

  // ---------------- phase 0: LayerNorm (one thread per position) ----------------
  {
    const float* zr = z + (((i << 8) + tid) << 5);
    float x[32];
#pragma unroll
    for (int e = 0; e < 8; e++) {
      const float4 v = *(const float4*)(zr + e*4);
      x[4*e] = v.x; x[4*e+1] = v.y; x[4*e+2] = v.z; x[4*e+3] = v.w;
    }
    float mu = 0.f;
#pragma unroll
    for (int c = 0; c < 32; c++) mu += x[c];
    mu *= (1.f / 32.f);
    float s2 = 0.f;
#pragma unroll
    for (int c = 0; c < 32; c++) { float d = x[c] - mu; s2 += d * d; }
    const float rstd = rsqrtf(s2 * (1.f / 32.f) + 1e-5f);
    u32* dst = (u32*)&sZ[tid][0];
#pragma unroll
    for (int e = 0; e < 16; e++) {
      const float za = (x[2*e]   - mu) * rstd * ln_g[2*e]   + ln_b[2*e];
      const float zb = (x[2*e+1] - mu) * rstd * ln_g[2*e+1] + ln_b[2*e+1];
      dst[e] = pk(za, zb);
    }
  }
  __syncthreads();

  f32x4 acc[2][2] = {{z4, z4}, {z4, z4}};   // fp32 out accumulators (across heads)
  const float k2e = 0.17677669529663687f * 1.44269504089f;   // (1/sqrt32)*log2(e)

  for (int h = 0; h < 4; ++h) {
    // weight fragments (f32 -> bf16 pack), loaded once per head (L1/L2-hot)
    auto ldw = [&](const float* W, int cb) -> U8 {
      const float* p = W + h*1024 + (cb*16 + col)*32 + quad*8;
      const float4 a = *(const float4*)(p);
      const float4 b = *(const float4*)(p + 4);
      U8 t;
      t.u[0] = pk(a.x, a.y); t.u[1] = pk(a.z, a.w);
      t.u[2] = pk(b.x, b.y); t.u[3] = pk(b.z, b.w);
      return t;
    };

    // -------- Q/G pre-phase: this block's 128 queries (2 tiles/wave) --------
    // (needed before half-0 attention; reads sZ which is stable all kernel)
    U8    QB[2];        // Q (pre-scaled) permuted-k B-frags
    float G[2][8];      // gates, O^T C-layout
    {
      const U8 WqF0 = ldw(Wq,0), WqF1 = ldw(Wq,1);
      const U8 WgF0 = ldw(Wg,0), WgF1 = ldw(Wg,1);
      float bgl[8];
#pragma unroll
      for (int r = 0; r < 4; r++) {
        bgl[r]     = bg[h*32 + quad*4 + r];
        bgl[4 + r] = bg[h*32 + 16 + quad*4 + r];
      }
#pragma unroll
      for (int p2 = 0; p2 < 2; p2++) {
        const int row = qhalf*128 + (p2*4 + wave)*16 + col;
        U8 ZA;
        {
          const uint4 v = *(const uint4*)&sZ[row][quad*8];
          ZA.u[0] = v.x; ZA.u[1] = v.y; ZA.u[2] = v.z; ZA.u[3] = v.w;
        }
        const f32x4 q0 = mfma16(WqF0.b, ZA.b, z4);
        const f32x4 q1 = mfma16(WqF1.b, ZA.b, z4);
        const f32x4 g0 = mfma16(WgF0.b, ZA.b, z4);
        const f32x4 g1 = mfma16(WgF1.b, ZA.b, z4);
        QB[p2].u[0] = pk(q0[0]*k2e, q0[1]*k2e); QB[p2].u[1] = pk(q0[2]*k2e, q0[3]*k2e);
        QB[p2].u[2] = pk(q1[0]*k2e, q1[1]*k2e); QB[p2].u[3] = pk(q1[2]*k2e, q1[3]*k2e);
#pragma unroll
        for (int r = 0; r < 4; r++) {
          G[p2][r]     = 1.f / (1.f + __expf(-(g0[r] + bgl[r])));
          G[p2][4 + r] = 1.f / (1.f + __expf(-(g1[r] + bgl[4 + r])));
        }
      }
    }

    const U8 WkF0 = ldw(Wk,0), WkF1 = ldw(Wk,1);
    const U8 WvF0 = ldw(Wv,0), WvF1 = ldw(Wv,1);

    float l[2]     = {0.f, 0.f};
    f32x4 O[2][2]  = {{z4, z4}, {z4, z4}};   // O^T per p2: ch=quad*4+r (+16), q=col

    // -------- two 128-key halves: project -> sync -> attend -> sync --------
#pragma unroll
    for (int m = 0; m < 2; m++) {
      // projection of keys m*128 .. m*128+127 (4 waves x 2 tiles of 16)
#pragma unroll
      for (int pp = 0; pp < 2; pp++) {
        const int lbase = (pp*4 + wave) * 16;        // local key base (0..112)
        const int grow  = m*128 + lbase + col;       // global position
        U8 ZA;
        {
          const uint4 v = *(const uint4*)&sZ[grow][quad*8];
          ZA.u[0] = v.x; ZA.u[1] = v.y; ZA.u[2] = v.z; ZA.u[3] = v.w;
        }
        // K^T (C-layout: ch=quad*4+reg, key=col), V (key=quad*4+reg, ch=col)
        const f32x4 k0 = mfma16(WkF0.b, ZA.b, z4);
        const f32x4 k1 = mfma16(WkF1.b, ZA.b, z4);
        const f32x4 v0 = mfma16(ZA.b, WvF0.b, z4);
        const f32x4 v1 = mfma16(ZA.b, WvF1.b, z4);
        *(uint2*)&sK[lbase + col][quad*4]        = make_uint2(pk(k0[0],k0[1]), pk(k0[2],k0[3]));
        *(uint2*)&sK[lbase + col][16 + quad*4]   = make_uint2(pk(k1[0],k1[1]), pk(k1[2],k1[3]));
        *(uint2*)&sVt[col][lbase + quad*4]       = make_uint2(pk(v0[0],v0[1]), pk(v0[2],v0[3]));
        *(uint2*)&sVt[16 + col][lbase + quad*4]  = make_uint2(pk(v1[0],v1[1]), pk(v1[2],v1[3]));
      }
      __syncthreads();

      // attention over this half's 128 keys, both q-tiles
#pragma unroll
      for (int p2 = 0; p2 < 2; p2++) {
#pragma unroll
        for (int kb = 0; kb < 128; kb += 32) {
          U8 KF0, KF1;
          {
            const uint2 a = *(const uint2*)&sK[kb + col][quad*4];
            const uint2 b = *(const uint2*)&sK[kb + col][16 + quad*4];
            KF0.u[0] = a.x; KF0.u[1] = a.y; KF0.u[2] = b.x; KF0.u[3] = b.y;
            const uint2 c = *(const uint2*)&sK[kb + 16 + col][quad*4];
            const uint2 d = *(const uint2*)&sK[kb + 16 + col][16 + quad*4];
            KF1.u[0] = c.x; KF1.u[1] = c.y; KF1.u[2] = d.x; KF1.u[3] = d.y;
          }
          const f32x4 S0 = mfma16(KF0.b, QB[p2].b, z4);   // keys kb+quad*4+r
          const f32x4 S1 = mfma16(KF1.b, QB[p2].b, z4);   // keys kb+16+quad*4+r
          float ps[8];
#pragma unroll
          for (int r = 0; r < 4; r++) {
            ps[r]     = exp2f(S0[r]);     // scale pre-folded into Q; no clamp needed
            ps[4 + r] = exp2f(S1[r]);
          }
          l[p2] += ((ps[0]+ps[1]) + (ps[2]+ps[3])) + ((ps[4]+ps[5]) + (ps[6]+ps[7]));
          U8 PB;
          PB.u[0] = pk(ps[0],ps[1]); PB.u[1] = pk(ps[2],ps[3]);
          PB.u[2] = pk(ps[4],ps[5]); PB.u[3] = pk(ps[6],ps[7]);
          U8 VF0, VF1;
          {
            const uint2 a = *(const uint2*)&sVt[col][kb + quad*4];
            const uint2 b = *(const uint2*)&sVt[col][kb + 16 + quad*4];
            VF0.u[0] = a.x; VF0.u[1] = a.y; VF0.u[2] = b.x; VF0.u[3] = b.y;
            const uint2 c = *(const uint2*)&sVt[16 + col][kb + quad*4];
            const uint2 d = *(const uint2*)&sVt[16 + col][kb + 16 + quad*4];
            VF1.u[0] = c.x; VF1.u[1] = c.y; VF1.u[2] = d.x; VF1.u[3] = d.y;
          }
          O[p2][0] = mfma16(VF0.b, PB.b, O[p2][0]);
          O[p2][1] = mfma16(VF1.b, PB.b, O[p2][1]);
        }
      }
      __syncthreads();   // protect sK/sVt before the next half / head overwrites
    }

    // -------- epilogue: normalize, gate, fused out-projection --------
    U8 WoA0, WoA1;   // Wo A-frags with matching k-permutation (qt-invariant)
    {
      const float4 a = *(const float4*)(Wo + col*128 + h*32 + quad*4);
      const float4 b = *(const float4*)(Wo + col*128 + h*32 + 16 + quad*4);
      WoA0.u[0] = pk(a.x,a.y); WoA0.u[1] = pk(a.z,a.w);
      WoA0.u[2] = pk(b.x,b.y); WoA0.u[3] = pk(b.z,b.w);
      const float4 c = *(const float4*)(Wo + (16 + col)*128 + h*32 + quad*4);
      const float4 d = *(const float4*)(Wo + (16 + col)*128 + h*32 + 16 + quad*4);
      WoA1.u[0] = pk(c.x,c.y); WoA1.u[1] = pk(c.z,c.w);
      WoA1.u[2] = pk(d.x,d.y); WoA1.u[3] = pk(d.z,d.w);
    }
#pragma unroll
    for (int p2 = 0; p2 < 2; p2++) {
      float lv = l[p2];
      lv += __shfl_xor(lv, 16);   // reduce over quads (keys spread reg-dim x quad)
      lv += __shfl_xor(lv, 32);
      const float inv = 1.f / lv;
      float og[8];
#pragma unroll
      for (int r = 0; r < 4; r++) {
        og[r]     = O[p2][0][r] * inv * G[p2][r];
        og[4 + r] = O[p2][1][r] * inv * G[p2][4 + r];
      }
      U8 OB;   // gated O^T as permuted-k B-frag (k-permutation matches WoA)
      OB.u[0] = pk(og[0],og[1]); OB.u[1] = pk(og[2],og[3]);
      OB.u[2] = pk(og[4],og[5]); OB.u[3] = pk(og[6],og[7]);
      acc[p2][0] = mfma16(WoA0.b, OB.b, acc[p2][0]);   // couts 0..15
      acc[p2][1] = mfma16(WoA1.b, OB.b, acc[p2][1]);   // couts 16..31
    }
  }

  // ---------------- epilogue: + bo, float4 stores ----------------
  float bo0[4], bo1[4];
#pragma unroll
  for (int r = 0; r < 4; r++) {
    bo0[r] = bo[quad*4 + r];
    bo1[r] = bo[16 + quad*4 + r];
  }
#pragma unroll
  for (int p2 = 0; p2 < 2; p2++) {
    const int pos = (i << 8) + qhalf*128 + (p2*4 + wave)*16 + col;
    float* op = out + pos*32;
    *(float4*)(op + quad*4)      = make_float4(acc[p2][0][0] + bo0[0], acc[p2][0][1] + bo0[1],
                                               acc[p2][0][2] + bo0[2], acc[p2][0][3] + bo0[3]);
    *(float4*)(op + 16 + quad*4) = make_float4(acc[p2][1][0] + bo1[0], acc[p2][1][1] + bo1[1],
                                               acc[p2][1][2] + bo1[2], acc[p2][1][3] + bo1[3]);
  }
}

extern "C" void kernel_launch(void* const* d_in, const int* in_sizes, int n_in,
                              void* d_out, int out_size, void* d_ws, size_t ws_size,
                              hipStream_t stream)
{
  const float* z    = (const float*)d_in[0];
  const float* ln_g = (const float*)d_in[1];
  const float* ln_b = (const float*)d_in[2];
  const float* Wq   = (const float*)d_in[3];
  const float* Wk   = (const float*)d_in[4];
  const float* Wv   = (const float*)d_in[5];
  // d_in[6] = Wb: softmax shift invariance -> exactly cancels, unused.
  const float* Wg   = (const float*)d_in[7];
  const float* bg   = (const float*)d_in[8];
  const float* Wo   = (const float*)d_in[9];
  const float* bo   = (const float*)d_in[10];

  tri_attn_fused<<<dim3(2, 256), 256, 0, stream>>>(z, ln_g, ln_b, Wq, Wk, Wv, Wg, bg, Wo, bo,
                                                   (float*)d_out);
}